// Round 4
// baseline (10061.230 us; speedup 1.0000x reference)
//
#include <hip/hip_runtime.h>
#include <hip/hip_bf16.h>

// ---------------------------------------------------------------------------
// BiLSTM T=512 B=64 D=H=512, both scans run forward (reference bug preserved).
// R4 (= R3 with compile fix): h-part W in VGPRs (128 regs), x-part W in LDS;
// distributed per-direction flag barrier; deferred NT out-stores (ext_vector
// type, not HIP float4); packed agent-scope h publication; x-part GEMM of
// t+1 overlapped with the wait.
// ---------------------------------------------------------------------------

typedef short s8v __attribute__((ext_vector_type(8)));   // 8 x bf16 bits
typedef float f4v __attribute__((ext_vector_type(4)));

#define T_STEPS 512
#define BATCH   64
#define KDIM    1024          // D + H
#define NB_DIR  64            // blocks per direction
#define HS      8             // hidden units per block
#define COLS    32            // 4 gates * HS
#define NBLK    (2*NB_DIR)
#define WXP     520           // x-part W LDS pitch (ushort): 512 + 8 pad

// workspace byte offsets
#define WS_XB   0u                      // x bf16: 512*64*512*2      = 33554432
#define WS_WT   33554432u               // Wt bf16: 2*64*32*1024*2   =  8388608
#define WS_BIAS 41943040u               // bias f32: 2*2048*4        =    16384
#define WS_HBUF 41959424u               // hbuf bf16: 2*2*64*512*2   =   262144
#define WS_FLG  42221568u               // 128 flag dwords (2 dirs x 64 blocks)

__device__ __forceinline__ ushort f2bf(float f) {
  unsigned u = __builtin_bit_cast(unsigned, f);
  unsigned r = u + 0x7FFFu + ((u >> 16) & 1u);   // RNE
  return (ushort)(r >> 16);
}

__global__ __launch_bounds__(256) void k_xcvt(const float* __restrict__ x,
                                              ushort* __restrict__ xb, int n8) {
  int i = blockIdx.x * 256 + threadIdx.x;
  if (i >= n8) return;
  size_t off = (size_t)i * 8;
  float4 a = *reinterpret_cast<const float4*>(x + off);
  float4 b = *reinterpret_cast<const float4*>(x + off + 4);
  s8v o;
  o[0] = (short)f2bf(a.x); o[1] = (short)f2bf(a.y);
  o[2] = (short)f2bf(a.z); o[3] = (short)f2bf(a.w);
  o[4] = (short)f2bf(b.x); o[5] = (short)f2bf(b.y);
  o[6] = (short)f2bf(b.z); o[7] = (short)f2bf(b.w);
  *reinterpret_cast<s8v*>(xb + off) = o;
}

// Build permuted W^T (bf16): Wt[d][nb][p][k], p = gate*8+u, k<512 from Wih,
// k>=512 from Whh. One thread per (d, col); k-contiguous 16B stores.
__global__ __launch_bounds__(256) void k_wtprep(const float* __restrict__ WihF,
                                                const float* __restrict__ WhhF,
                                                const float* __restrict__ WihB,
                                                const float* __restrict__ WhhB,
                                                ushort* __restrict__ Wt) {
  int g = blockIdx.x * 256 + threadIdx.x;       // 0..4095
  int d = g >> 11, col = g & 2047;
  const float* Wih = d ? WihB : WihF;
  const float* Whh = d ? WhhB : WhhF;
  int gate = col >> 9, j = col & 511;
  int nb = j >> 3, u = j & 7, p = (gate << 3) | u;
  ushort* dst = Wt + (((size_t)(d * NB_DIR + nb) * COLS + p) << 10);
  for (int k0 = 0; k0 < KDIM; k0 += 8) {
    s8v o;
#pragma unroll
    for (int i = 0; i < 8; ++i) {
      int k = k0 + i;
      float v = (k < 512) ? Wih[k * 2048 + col] : Whh[(k - 512) * 2048 + col];
      o[i] = (short)f2bf(v);
    }
    *reinterpret_cast<s8v*>(dst + k0) = o;
  }
}

__global__ __launch_bounds__(256) void k_init(const float* __restrict__ bihF,
                                              const float* __restrict__ bhhF,
                                              const float* __restrict__ bihB,
                                              const float* __restrict__ bhhB,
                                              float* __restrict__ bias,
                                              unsigned* __restrict__ hbuf_u32,
                                              unsigned* __restrict__ flg) {
  int g = blockIdx.x * 256 + threadIdx.x;
  if (g < 65536) hbuf_u32[g] = 0u;              // zero both h ping-pong bufs
  if (g < 2048) {
    bias[g]        = bihF[g] + bhhF[g];
    bias[2048 + g] = bihB[g] + bhhB[g];
  }
  if (g < 128) flg[g] = 0u;
}

__global__ __launch_bounds__(256, 1) void k_lstm(const ushort* __restrict__ xb,
                                                 const ushort* __restrict__ Wt,
                                                 const float* __restrict__ bias,
                                                 ushort* hbuf,
                                                 float* __restrict__ out,
                                                 unsigned* flags) {
  __shared__ ushort Wx[COLS][WXP];              // x-part W, 33.3 KB
  __shared__ float gates[BATCH][COLS + 1];      // 8.4 KB
  __shared__ float cst[BATCH][HS];              // persistent c state
  __shared__ float hlds[BATCH][HS];             // h of this step (for out)
  __shared__ float biasl[COLS];

  const int tid  = threadIdx.x;
  const int dir  = blockIdx.x & 1;
  const int nb   = blockIdx.x >> 1;
  const int lane = tid & 63;
  const int w    = tid >> 6;                    // wave id == m-tile
  const int j0   = nb * HS;
  const int pc   = lane & 15;                   // frag col within n-tile
  const int kgrp = (lane >> 4) << 3;            // 0,8,16,24

  const ushort* wsrc = Wt + ((size_t)(dir * NB_DIR + nb) << 15);
  // stage x-part W (k = 0..511) into LDS
  for (int v = tid; v < COLS * 64; v += 256) {
    int p = v >> 6, kk = (v & 63) << 3;
    *reinterpret_cast<s8v*>(&Wx[p][kk]) =
        *reinterpret_cast<const s8v*>(wsrc + ((size_t)p << 10) + kk);
  }
  // h-part B fragments (k = 512..1023) into registers: 32 s8v = 128 VGPR
  s8v bh0[16], bh1[16];
#pragma unroll
  for (int kb = 0; kb < 16; ++kb) {
    bh0[kb] = *reinterpret_cast<const s8v*>(
        wsrc + ((size_t)pc << 10) + 512 + (kb << 5) + kgrp);
    bh1[kb] = *reinterpret_cast<const s8v*>(
        wsrc + ((size_t)(16 + pc) << 10) + 512 + (kb << 5) + kgrp);
  }

  if (tid < COLS)
    biasl[tid] = bias[dir * 2048 + ((tid >> 3) << 9) + j0 + (tid & 7)];
  for (int v = tid; v < BATCH * HS; v += 256) cst[v >> 3][v & 7] = 0.f;
  __syncthreads();

  const int arow = (w << 4) + (lane & 15);      // batch row for A frags

  float* outH  = out;                            // [512][64][1024]
  float* outHn = out + (size_t)33554432;
  float* outCn = outHn + 65536;
  unsigned* myflag   = flags + (dir << 6) + nb;
  unsigned* dirflags = flags + (dir << 6);

  // ---- prologue: x-part for t=0 (from LDS)
  f4v acc0 = {0.f, 0.f, 0.f, 0.f}, acc1 = {0.f, 0.f, 0.f, 0.f};
  {
    const ushort* xa = xb + ((size_t)arow << 9) + kgrp;
#pragma unroll
    for (int kb = 0; kb < 16; ++kb) {
      s8v a  = *reinterpret_cast<const s8v*>(xa + (kb << 5));
      s8v wb0 = *reinterpret_cast<const s8v*>(&Wx[pc][(kb << 5) + kgrp]);
      s8v wb1 = *reinterpret_cast<const s8v*>(&Wx[16 + pc][(kb << 5) + kgrp]);
      acc0 = __builtin_amdgcn_mfma_f32_16x16x32_bf16(a, wb0, acc0, 0, 0, 0);
      acc1 = __builtin_amdgcn_mfma_f32_16x16x32_bf16(a, wb1, acc1, 0, 0, 0);
    }
  }

  for (int t = 0; t < T_STEPS; ++t) {
    if (t > 0) {
      if (tid < 64) {                            // parallel flag poll (own dir)
        unsigned tgt = (unsigned)t;
        while (__hip_atomic_load(&dirflags[tid], __ATOMIC_RELAXED,
                                 __HIP_MEMORY_SCOPE_AGENT) < tgt)
          __builtin_amdgcn_s_sleep(1);
      }
      __syncthreads();
      __threadfence();                           // acquire: invalidate caches
    }
    // ---- h-part GEMM (critical path, B from registers)
    const ushort* ha = hbuf +
        ((size_t)(((dir << 1) | ((t + 1) & 1)) * BATCH + arow) << 9) + kgrp;
#pragma unroll
    for (int kb = 0; kb < 16; ++kb) {
      s8v a = *reinterpret_cast<const s8v*>(ha + (kb << 5));
      acc0 = __builtin_amdgcn_mfma_f32_16x16x32_bf16(a, bh0[kb], acc0, 0, 0, 0);
      acc1 = __builtin_amdgcn_mfma_f32_16x16x32_bf16(a, bh1[kb], acc1, 0, 0, 0);
    }
    // D layout: col = lane&15, row = (lane>>4)*4 + reg  [m89-verified]
    {
      int r0 = (w << 4) + ((lane >> 4) << 2);
#pragma unroll
      for (int r = 0; r < 4; ++r) {
        gates[r0 + r][pc]      = acc0[r];
        gates[r0 + r][16 + pc] = acc1[r];
      }
    }
    __syncthreads();
    // ---- elementwise: each thread owns (b, 2 units); pack dword for hbuf
    {
      int b = tid >> 2, up = (tid & 3) << 1;
      float h2[2], c2[2];
#pragma unroll
      for (int e = 0; e < 2; ++e) {
        int u = up + e;
        float ig = gates[b][u]      + biasl[u];
        float fg = gates[b][8 + u]  + biasl[8 + u];
        float gg = gates[b][16 + u] + biasl[16 + u];
        float og = gates[b][24 + u] + biasl[24 + u];
        float cp = cst[b][u];
        float si = 1.f / (1.f + __expf(-ig));
        float sf = 1.f / (1.f + __expf(-fg));
        float so = 1.f / (1.f + __expf(-og));
        float tg = 1.f - 2.f / (__expf(2.f * gg) + 1.f);
        float c  = sf * cp + si * tg;
        float tc = 1.f - 2.f / (__expf(2.f * c) + 1.f);
        float h  = so * tc;
        cst[b][u] = c;
        hlds[b][u] = h;
        h2[e] = h; c2[e] = c;
      }
      unsigned pk = (unsigned)f2bf(h2[0]) | ((unsigned)f2bf(h2[1]) << 16);
      unsigned* hb = (unsigned*)(hbuf +
          ((size_t)(((dir << 1) | (t & 1)) * BATCH + b) << 9) + j0 + up);
      __hip_atomic_store(hb, pk, __ATOMIC_RELAXED, __HIP_MEMORY_SCOPE_AGENT);
      if (t == T_STEPS - 1) {
        size_t oc = ((size_t)b << 10) + (dir << 9) + j0 + up;
        __builtin_nontemporal_store(h2[0], outHn + oc);
        __builtin_nontemporal_store(h2[1], outHn + oc + 1);
        __builtin_nontemporal_store(c2[0], outCn + oc);
        __builtin_nontemporal_store(c2[1], outCn + oc + 1);
      }
    }
    __syncthreads();                             // drains hbuf stores
    if (tid == 0) {
      __threadfence();                           // release: writeback
      __hip_atomic_store(myflag, (unsigned)(t + 1), __ATOMIC_RELEASE,
                         __HIP_MEMORY_SCOPE_AGENT);
    }
    // ---- deferred, off-critical-path: out h stores for step t (NT)
    if (tid < 64) {
      const f4v* hp = reinterpret_cast<const f4v*>(&hlds[tid][0]);
      f4v v0 = hp[0], v1 = hp[1];
      float* dst = outH + ((size_t)t << 16) + ((size_t)tid << 10) + (dir << 9) + j0;
      __builtin_nontemporal_store(v0, reinterpret_cast<f4v*>(dst));
      __builtin_nontemporal_store(v1, reinterpret_cast<f4v*>(dst + 4));
    }
    // ---- x-part for t+1 (from LDS), overlapped with other blocks' progress
    acc0 = (f4v){0.f, 0.f, 0.f, 0.f};
    acc1 = (f4v){0.f, 0.f, 0.f, 0.f};
    if (t < T_STEPS - 1) {
      const ushort* xa = xb + (((size_t)(t + 1) * BATCH + arow) << 9) + kgrp;
#pragma unroll
      for (int kb = 0; kb < 16; ++kb) {
        s8v a  = *reinterpret_cast<const s8v*>(xa + (kb << 5));
        s8v wb0 = *reinterpret_cast<const s8v*>(&Wx[pc][(kb << 5) + kgrp]);
        s8v wb1 = *reinterpret_cast<const s8v*>(&Wx[16 + pc][(kb << 5) + kgrp]);
        acc0 = __builtin_amdgcn_mfma_f32_16x16x32_bf16(a, wb0, acc0, 0, 0, 0);
        acc1 = __builtin_amdgcn_mfma_f32_16x16x32_bf16(a, wb1, acc1, 0, 0, 0);
      }
    }
  }
}

extern "C" void kernel_launch(void* const* d_in, const int* in_sizes, int n_in,
                              void* d_out, int out_size, void* d_ws, size_t ws_size,
                              hipStream_t stream) {
  const float* x    = (const float*)d_in[0];
  const float* WihF = (const float*)d_in[1];
  const float* WhhF = (const float*)d_in[2];
  const float* bihF = (const float*)d_in[3];
  const float* bhhF = (const float*)d_in[4];
  const float* WihB = (const float*)d_in[5];
  const float* WhhB = (const float*)d_in[6];
  const float* bihB = (const float*)d_in[7];
  const float* bhhB = (const float*)d_in[8];

  char* ws = (char*)d_ws;
  ushort*   xb   = (ushort*)(ws + WS_XB);
  ushort*   Wt   = (ushort*)(ws + WS_WT);
  float*    bias = (float*)(ws + WS_BIAS);
  ushort*   hbuf = (ushort*)(ws + WS_HBUF);
  unsigned* flg  = (unsigned*)(ws + WS_FLG);

  k_xcvt<<<8192, 256, 0, stream>>>(x, xb, 2097152);
  k_wtprep<<<16, 256, 0, stream>>>(WihF, WhhF, WihB, WhhB, Wt);
  k_init<<<256, 256, 0, stream>>>(bihF, bhhF, bihB, bhhB, bias,
                                  (unsigned*)hbuf, flg);
  k_lstm<<<NBLK, 256, 0, stream>>>(xb, Wt, bias, hbuf, (float*)d_out, flg);
}

// Round 6
// 4163.524 us; speedup vs baseline: 2.4165x; 2.4165x over previous
//
#include <hip/hip_runtime.h>
#include <hip/hip_bf16.h>

// ---------------------------------------------------------------------------
// BiLSTM T=512 B=64 D=H=512, both scans run forward (reference bug preserved).
// R6 (= R5 + s_sleep in poll): fence-free flag sync. h published via
// write-through agent atomics and READ via agent-scope relaxed atomic b64
// loads (bypass L1/L2 => always fresh, no buffer_inv); flag store relaxed
// (h data drained to coherence point by pre-flag __syncthreads vmcnt(0)).
// W fully LDS-resident; distributed per-direction flags; deferred NT
// out-stores; x-part GEMM of t+1 overlapped. Poll uses s_sleep(1) — tight
// spins (R2/R5) correlate with container-killing livelock at the coherence
// point; sleeping polls (R1/R4) always passed.
// ---------------------------------------------------------------------------

typedef short s8v __attribute__((ext_vector_type(8)));   // 8 x bf16 bits
typedef float f4v __attribute__((ext_vector_type(4)));
typedef unsigned long long u2v __attribute__((ext_vector_type(2)));

#define T_STEPS 512
#define BATCH   64
#define KDIM    1024          // D + H
#define NB_DIR  64            // blocks per direction
#define HS      8             // hidden units per block
#define COLS    32            // 4 gates * HS
#define NBLK    (2*NB_DIR)
#define WP      1032          // W LDS pitch (ushort): 1024 + 8 pad

// workspace byte offsets
#define WS_XB   0u                      // x bf16: 512*64*512*2      = 33554432
#define WS_WT   33554432u               // Wt bf16: 2*64*32*1024*2   =  8388608
#define WS_BIAS 41943040u               // bias f32: 2*2048*4        =    16384
#define WS_HBUF 41959424u               // hbuf bf16: 2*2*64*512*2   =   262144
#define WS_FLG  42221568u               // 128 flag dwords (2 dirs x 64 blocks)

__device__ __forceinline__ ushort f2bf(float f) {
  unsigned u = __builtin_bit_cast(unsigned, f);
  unsigned r = u + 0x7FFFu + ((u >> 16) & 1u);   // RNE
  return (ushort)(r >> 16);
}

__global__ __launch_bounds__(256) void k_xcvt(const float* __restrict__ x,
                                              ushort* __restrict__ xb, int n8) {
  int i = blockIdx.x * 256 + threadIdx.x;
  if (i >= n8) return;
  size_t off = (size_t)i * 8;
  float4 a = *reinterpret_cast<const float4*>(x + off);
  float4 b = *reinterpret_cast<const float4*>(x + off + 4);
  s8v o;
  o[0] = (short)f2bf(a.x); o[1] = (short)f2bf(a.y);
  o[2] = (short)f2bf(a.z); o[3] = (short)f2bf(a.w);
  o[4] = (short)f2bf(b.x); o[5] = (short)f2bf(b.y);
  o[6] = (short)f2bf(b.z); o[7] = (short)f2bf(b.w);
  *reinterpret_cast<s8v*>(xb + off) = o;
}

// Build permuted W^T (bf16): Wt[d][nb][p][k], p = gate*8+u, k<512 from Wih,
// k>=512 from Whh. One thread per (d, col); k-contiguous 16B stores.
__global__ __launch_bounds__(256) void k_wtprep(const float* __restrict__ WihF,
                                                const float* __restrict__ WhhF,
                                                const float* __restrict__ WihB,
                                                const float* __restrict__ WhhB,
                                                ushort* __restrict__ Wt) {
  int g = blockIdx.x * 256 + threadIdx.x;       // 0..4095
  int d = g >> 11, col = g & 2047;
  const float* Wih = d ? WihB : WihF;
  const float* Whh = d ? WhhB : WhhF;
  int gate = col >> 9, j = col & 511;
  int nb = j >> 3, u = j & 7, p = (gate << 3) | u;
  ushort* dst = Wt + (((size_t)(d * NB_DIR + nb) * COLS + p) << 10);
  for (int k0 = 0; k0 < KDIM; k0 += 8) {
    s8v o;
#pragma unroll
    for (int i = 0; i < 8; ++i) {
      int k = k0 + i;
      float v = (k < 512) ? Wih[k * 2048 + col] : Whh[(k - 512) * 2048 + col];
      o[i] = (short)f2bf(v);
    }
    *reinterpret_cast<s8v*>(dst + k0) = o;
  }
}

__global__ __launch_bounds__(256) void k_init(const float* __restrict__ bihF,
                                              const float* __restrict__ bhhF,
                                              const float* __restrict__ bihB,
                                              const float* __restrict__ bhhB,
                                              float* __restrict__ bias,
                                              unsigned* __restrict__ hbuf_u32,
                                              unsigned* __restrict__ flg) {
  int g = blockIdx.x * 256 + threadIdx.x;
  if (g < 65536) hbuf_u32[g] = 0u;              // zero both h ping-pong bufs
  if (g < 2048) {
    bias[g]        = bihF[g] + bhhF[g];
    bias[2048 + g] = bihB[g] + bhhB[g];
  }
  if (g < 128) flg[g] = 0u;
}

__global__ __launch_bounds__(256, 1) void k_lstm(const ushort* __restrict__ xb,
                                                 const ushort* __restrict__ Wt,
                                                 const float* __restrict__ bias,
                                                 ushort* hbuf,
                                                 float* __restrict__ out,
                                                 unsigned* flags) {
  __shared__ ushort Wlds[COLS][WP];             // 66 KB, full W slice
  __shared__ float gates[BATCH][COLS + 1];      // 8.4 KB
  __shared__ float cst[BATCH][HS];              // persistent c state
  __shared__ float hlds[BATCH][HS];             // h of this step (for out)
  __shared__ float biasl[COLS];

  const int tid  = threadIdx.x;
  const int dir  = blockIdx.x & 1;
  const int nb   = blockIdx.x >> 1;
  const int lane = tid & 63;
  const int w    = tid >> 6;                    // wave id == m-tile
  const int j0   = nb * HS;
  const int pc   = lane & 15;                   // frag col within n-tile
  const int kgrp = (lane >> 4) << 3;            // 0,8,16,24

  // stage full W slice (global -> LDS), once
  const ushort* wsrc = Wt + ((size_t)(dir * NB_DIR + nb) << 15);
  for (int v = tid; v < COLS * 128; v += 256) {
    int p = v >> 7, kk = (v & 127) << 3;
    *reinterpret_cast<s8v*>(&Wlds[p][kk]) =
        *reinterpret_cast<const s8v*>(wsrc + (p << 10) + kk);
  }
  if (tid < COLS)
    biasl[tid] = bias[dir * 2048 + ((tid >> 3) << 9) + j0 + (tid & 7)];
  for (int v = tid; v < BATCH * HS; v += 256) cst[v >> 3][v & 7] = 0.f;
  __syncthreads();

  const int arow = (w << 4) + (lane & 15);      // batch row for A frags

  float* outH  = out;                            // [512][64][1024]
  float* outHn = out + (size_t)33554432;
  float* outCn = outHn + 65536;
  unsigned* myflag   = flags + (dir << 6) + nb;
  unsigned* dirflags = flags + (dir << 6);

  // ---- prologue: x-part for t=0 (from LDS)
  f4v acc0 = {0.f, 0.f, 0.f, 0.f}, acc1 = {0.f, 0.f, 0.f, 0.f};
  {
    const ushort* xa = xb + ((size_t)arow << 9) + kgrp;
#pragma unroll
    for (int kb = 0; kb < 16; ++kb) {
      s8v a  = *reinterpret_cast<const s8v*>(xa + (kb << 5));
      s8v wb0 = *reinterpret_cast<const s8v*>(&Wlds[pc][(kb << 5) + kgrp]);
      s8v wb1 = *reinterpret_cast<const s8v*>(&Wlds[16 + pc][(kb << 5) + kgrp]);
      acc0 = __builtin_amdgcn_mfma_f32_16x16x32_bf16(a, wb0, acc0, 0, 0, 0);
      acc1 = __builtin_amdgcn_mfma_f32_16x16x32_bf16(a, wb1, acc1, 0, 0, 0);
    }
  }

  for (int t = 0; t < T_STEPS; ++t) {
    if (t > 0) {
      if (tid < 64) {                            // parallel flag poll (own dir)
        unsigned tgt = (unsigned)t;
        while (__hip_atomic_load(&dirflags[tid], __ATOMIC_RELAXED,
                                 __HIP_MEMORY_SCOPE_AGENT) < tgt)
          __builtin_amdgcn_s_sleep(1);           // throttle: avoid fabric livelock
      }
      __syncthreads();                           // orders h-loads after poll
    }
    // ---- h-part GEMM (critical path). A-frags via cache-bypass atomic b64
    // loads (agent scope => sc0 sc1, reads coherence point; no buffer_inv).
    const ushort* ha = hbuf +
        ((size_t)(((dir << 1) | ((t + 1) & 1)) * BATCH + arow) << 9) + kgrp;
#pragma unroll
    for (int kb = 0; kb < 16; ++kb) {
      const unsigned long long* hq =
          reinterpret_cast<const unsigned long long*>(ha + (kb << 5));
      u2v q;
      q[0] = __hip_atomic_load(hq,     __ATOMIC_RELAXED, __HIP_MEMORY_SCOPE_AGENT);
      q[1] = __hip_atomic_load(hq + 1, __ATOMIC_RELAXED, __HIP_MEMORY_SCOPE_AGENT);
      s8v a = __builtin_bit_cast(s8v, q);
      s8v wb0 = *reinterpret_cast<const s8v*>(&Wlds[pc][512 + (kb << 5) + kgrp]);
      s8v wb1 = *reinterpret_cast<const s8v*>(&Wlds[16 + pc][512 + (kb << 5) + kgrp]);
      acc0 = __builtin_amdgcn_mfma_f32_16x16x32_bf16(a, wb0, acc0, 0, 0, 0);
      acc1 = __builtin_amdgcn_mfma_f32_16x16x32_bf16(a, wb1, acc1, 0, 0, 0);
    }
    // D layout: col = lane&15, row = (lane>>4)*4 + reg  [m89-verified]
    {
      int r0 = (w << 4) + ((lane >> 4) << 2);
#pragma unroll
      for (int r = 0; r < 4; ++r) {
        gates[r0 + r][pc]      = acc0[r];
        gates[r0 + r][16 + pc] = acc1[r];
      }
    }
    __syncthreads();
    // ---- elementwise: each thread owns (b, 2 units); pack dword for hbuf
    {
      int b = tid >> 2, up = (tid & 3) << 1;
      float h2[2], c2[2];
#pragma unroll
      for (int e = 0; e < 2; ++e) {
        int u = up + e;
        float ig = gates[b][u]      + biasl[u];
        float fg = gates[b][8 + u]  + biasl[8 + u];
        float gg = gates[b][16 + u] + biasl[16 + u];
        float og = gates[b][24 + u] + biasl[24 + u];
        float cp = cst[b][u];
        float si = 1.f / (1.f + __expf(-ig));
        float sf = 1.f / (1.f + __expf(-fg));
        float so = 1.f / (1.f + __expf(-og));
        float tg = 1.f - 2.f / (__expf(2.f * gg) + 1.f);
        float c  = sf * cp + si * tg;
        float tc = 1.f - 2.f / (__expf(2.f * c) + 1.f);
        float h  = so * tc;
        cst[b][u] = c;
        hlds[b][u] = h;
        h2[e] = h; c2[e] = c;
      }
      unsigned pk = (unsigned)f2bf(h2[0]) | ((unsigned)f2bf(h2[1]) << 16);
      unsigned* hb = (unsigned*)(hbuf +
          ((size_t)(((dir << 1) | (t & 1)) * BATCH + b) << 9) + j0 + up);
      __hip_atomic_store(hb, pk, __ATOMIC_RELAXED, __HIP_MEMORY_SCOPE_AGENT);
      if (t == T_STEPS - 1) {
        size_t oc = ((size_t)b << 10) + (dir << 9) + j0 + up;
        __builtin_nontemporal_store(h2[0], outHn + oc);
        __builtin_nontemporal_store(h2[1], outHn + oc + 1);
        __builtin_nontemporal_store(c2[0], outCn + oc);
        __builtin_nontemporal_store(c2[1], outCn + oc + 1);
      }
    }
    // barrier emits s_waitcnt vmcnt(0): all write-through hbuf stores are at
    // the coherence point before any thread proceeds => relaxed flag is safe.
    __syncthreads();
    if (tid == 0)
      __hip_atomic_store(myflag, (unsigned)(t + 1), __ATOMIC_RELAXED,
                         __HIP_MEMORY_SCOPE_AGENT);
    // ---- deferred, off-critical-path: out h stores for step t (NT)
    if (tid < 64) {
      const f4v* hp = reinterpret_cast<const f4v*>(&hlds[tid][0]);
      f4v v0 = hp[0], v1 = hp[1];
      float* dst = outH + ((size_t)t << 16) + ((size_t)tid << 10) + (dir << 9) + j0;
      __builtin_nontemporal_store(v0, reinterpret_cast<f4v*>(dst));
      __builtin_nontemporal_store(v1, reinterpret_cast<f4v*>(dst + 4));
    }
    // ---- x-part for t+1 (from LDS), overlapped with other blocks' progress
    acc0 = (f4v){0.f, 0.f, 0.f, 0.f};
    acc1 = (f4v){0.f, 0.f, 0.f, 0.f};
    if (t < T_STEPS - 1) {
      const ushort* xa = xb + (((size_t)(t + 1) * BATCH + arow) << 9) + kgrp;
#pragma unroll
      for (int kb = 0; kb < 16; ++kb) {
        s8v a  = *reinterpret_cast<const s8v*>(xa + (kb << 5));
        s8v wb0 = *reinterpret_cast<const s8v*>(&Wlds[pc][(kb << 5) + kgrp]);
        s8v wb1 = *reinterpret_cast<const s8v*>(&Wlds[16 + pc][(kb << 5) + kgrp]);
        acc0 = __builtin_amdgcn_mfma_f32_16x16x32_bf16(a, wb0, acc0, 0, 0, 0);
        acc1 = __builtin_amdgcn_mfma_f32_16x16x32_bf16(a, wb1, acc1, 0, 0, 0);
      }
    }
  }
}

extern "C" void kernel_launch(void* const* d_in, const int* in_sizes, int n_in,
                              void* d_out, int out_size, void* d_ws, size_t ws_size,
                              hipStream_t stream) {
  const float* x    = (const float*)d_in[0];
  const float* WihF = (const float*)d_in[1];
  const float* WhhF = (const float*)d_in[2];
  const float* bihF = (const float*)d_in[3];
  const float* bhhF = (const float*)d_in[4];
  const float* WihB = (const float*)d_in[5];
  const float* WhhB = (const float*)d_in[6];
  const float* bihB = (const float*)d_in[7];
  const float* bhhB = (const float*)d_in[8];

  char* ws = (char*)d_ws;
  ushort*   xb   = (ushort*)(ws + WS_XB);
  ushort*   Wt   = (ushort*)(ws + WS_WT);
  float*    bias = (float*)(ws + WS_BIAS);
  ushort*   hbuf = (ushort*)(ws + WS_HBUF);
  unsigned* flg  = (unsigned*)(ws + WS_FLG);

  k_xcvt<<<8192, 256, 0, stream>>>(x, xb, 2097152);
  k_wtprep<<<16, 256, 0, stream>>>(WihF, WhhF, WihB, WhhB, Wt);
  k_init<<<256, 256, 0, stream>>>(bihF, bhhF, bihB, bhhB, bias,
                                  (unsigned*)hbuf, flg);
  k_lstm<<<NBLK, 256, 0, stream>>>(xb, Wt, bias, hbuf, (float*)d_out, flg);
}